// Round 5
// baseline (81.611 us; speedup 1.0000x reference)
//
#include <hip/hip_runtime.h>

#define GRID_N 192
constexpr int NROWS = GRID_N * GRID_N;    // 36864 rows of 192 floats (h contiguous)
constexpr int RPB   = 16;                 // rows per block; block = one l, 16 consecutive w
constexpr int NBLK  = NROWS / RPB;        // 2304 blocks (12 per l-plane)
constexpr int RPW   = RPB / 4;            // 4 rows per wave

// Replicated accumulator: R copies of 1152 floats, replica = blockIdx % R.
//   [0..191]    hD   [192..383]  hM
//   [384..575]  lD   [576..767]  lM
//   [768..959]  wD   [960..1151] wM
constexpr int ACC_FLOATS = 1152;

#define LOAD_ROW(P, base) \
    P##0 = *(const float4*)(rvx + (base)); P##1 = *(const float4*)(vx + (base)); \
    P##2 = *(const float4*)(rvy + (base)); P##3 = *(const float4*)(vy + (base)); \
    P##4 = *(const float4*)(rvz + (base)); P##5 = *(const float4*)(vz + (base)); \
    P##6 = *(const float4*)(rp  + (base)); P##7 = *(const float4*)(p  + (base)); \
    P##8 = *(const float4*)(mask + (base));

__global__ __launch_bounds__(256, 8) void slice_main(
    const float* __restrict__ vx,  const float* __restrict__ vy,
    const float* __restrict__ vz,  const float* __restrict__ p,
    const float* __restrict__ mask,
    const float* __restrict__ rvx, const float* __restrict__ rvy,
    const float* __restrict__ rvz, const float* __restrict__ rp,
    float* __restrict__ acc, int R)
{
    const int tid  = threadIdx.x;
    const int wv   = tid >> 6;
    const int lane = tid & 63;
    const bool act = lane < 48;           // 48 lanes x float4 = one 192-float row
    const int hb   = lane << 2;

    float* __restrict__ racc = acc + (size_t)(blockIdx.x % R) * ACC_FLOATS;

    const int l  = blockIdx.x / 12;               // 12 blocks per l-plane
    const int w0 = (blockIdx.x % 12) * RPB;       // 16 consecutive w per block
    const int rowbase = l * GRID_N + w0 + wv * RPW;

    __shared__ float sD[4][192];
    __shared__ float sM[4][192];
    __shared__ float sRowD[RPB][49];              // [local w][lane], padded
    __shared__ float sRowM[RPB][49];
    __shared__ float sL[2][4];

    float cD0=0.f,cD1=0.f,cD2=0.f,cD3=0.f;
    float cM0=0.f,cM1=0.f,cM2=0.f,cM3=0.f;

    // process rows in pairs: 18 independent float4 loads issued per iter
#pragma unroll 1
    for (int i = 0; i < RPW / 2; ++i) {
        const int rowA = rowbase + 2 * i;
        float4 A0,A1,A2,A3,A4,A5,A6,A7,A8;
        float4 B0,B1,B2,B3,B4,B5,B6,B7,B8;
        if (act) {
            const size_t baseA = (size_t)rowA * GRID_N + hb;
            const size_t baseB = baseA + GRID_N;
            LOAD_ROW(A, baseA)
            LOAD_ROW(B, baseB)

            float dA0 = (A0.x-A1.x) + (A2.x-A3.x) + (A4.x-A5.x) + (A6.x-A7.x);
            float dA1 = (A0.y-A1.y) + (A2.y-A3.y) + (A4.y-A5.y) + (A6.y-A7.y);
            float dA2 = (A0.z-A1.z) + (A2.z-A3.z) + (A4.z-A5.z) + (A6.z-A7.z);
            float dA3 = (A0.w-A1.w) + (A2.w-A3.w) + (A4.w-A5.w) + (A6.w-A7.w);
            float dB0 = (B0.x-B1.x) + (B2.x-B3.x) + (B4.x-B5.x) + (B6.x-B7.x);
            float dB1 = (B0.y-B1.y) + (B2.y-B3.y) + (B4.y-B5.y) + (B6.y-B7.y);
            float dB2 = (B0.z-B1.z) + (B2.z-B3.z) + (B4.z-B5.z) + (B6.z-B7.z);
            float dB3 = (B0.w-B1.w) + (B2.w-B3.w) + (B4.w-B5.w) + (B6.w-B7.w);

            cD0 += dA0 + dB0; cD1 += dA1 + dB1;
            cD2 += dA2 + dB2; cD3 += dA3 + dB3;
            cM0 += A8.x + B8.x; cM1 += A8.y + B8.y;
            cM2 += A8.z + B8.z; cM3 += A8.w + B8.w;

            const int lr = wv * RPW + 2 * i;
            sRowD[lr][lane]     = (dA0 + dA1) + (dA2 + dA3);
            sRowM[lr][lane]     = (A8.x + A8.y) + (A8.z + A8.w);
            sRowD[lr + 1][lane] = (dB0 + dB1) + (dB2 + dB3);
            sRowM[lr + 1][lane] = (B8.x + B8.y) + (B8.z + B8.w);
        }
    }

    if (act) {
        sD[wv][hb+0]=cD0; sD[wv][hb+1]=cD1; sD[wv][hb+2]=cD2; sD[wv][hb+3]=cD3;
        sM[wv][hb+0]=cM0; sM[wv][hb+1]=cM1; sM[wv][hb+2]=cM2; sM[wv][hb+3]=cM3;
    }
    __syncthreads();

    // h columns: one atomic per h per block into this block's replica
    float d = 0.f, m = 0.f;
    if (tid < 192) {
        d = (sD[0][tid] + sD[1][tid]) + (sD[2][tid] + sD[3][tid]);
        m = (sM[0][tid] + sM[1][tid]) + (sM[2][tid] + sM[3][tid]);
        atomicAdd(&racc[tid],       d);
        atomicAdd(&racc[192 + tid], m);
    }
    // w slots: reduce sRow[w][0..47], one atomic pair per local w
    if (tid < RPB) {
        float wd = 0.f, wm = 0.f;
#pragma unroll 8
        for (int i = 0; i < 48; ++i) { wd += sRowD[tid][i]; wm += sRowM[tid][i]; }
        atomicAdd(&racc[768 + w0 + tid], wd);
        atomicAdd(&racc[960 + w0 + tid], wm);
    }
    // l plane-partial = sum of this block's h-column totals
    {
        float td = d, tm = m;
#pragma unroll
        for (int off = 32; off; off >>= 1) {
            td += __shfl_xor(td, off);
            tm += __shfl_xor(tm, off);
        }
        if (lane == 0) { sL[0][wv] = td; sL[1][wv] = tm; }
    }
    __syncthreads();
    if (tid == 0) {
        atomicAdd(&racc[384 + l], (sL[0][0]+sL[0][1])+(sL[0][2]+sL[0][3]));
        atomicAdd(&racc[576 + l], (sL[1][0]+sL[1][1])+(sL[1][2]+sL[1][3]));
    }
}

__global__ __launch_bounds__(1024) void slice_final(const float* __restrict__ acc,
                                                    float* __restrict__ out, int R)
{
    const int tid = threadIdx.x;
    __shared__ float ssum[ACC_FLOATS];
    __shared__ double sdbl[3];

    // phase 1: coalesced replica reduction (consecutive tid -> consecutive addr)
    for (int s = tid; s < ACC_FLOATS; s += 1024) {
        float v = 0.f;
        for (int r = 0; r < R; ++r) v += acc[(size_t)r * ACC_FLOATS + s];
        ssum[s] = v;
    }
    __syncthreads();

    // phase 2: per-slice terms in fp64, then mean
    if (tid < 192) {
        double term = (double)ssum[384 + tid] / (double)ssum[576 + tid]
                    + (double)ssum[768 + tid] / (double)ssum[960 + tid]
                    + (double)ssum[tid]       / (double)ssum[192 + tid];
#pragma unroll
        for (int off = 32; off; off >>= 1) term += __shfl_xor(term, off);
        if ((tid & 63) == 0) sdbl[tid >> 6] = term;
    }
    __syncthreads();
    if (tid == 0) out[0] = (float)((sdbl[0] + sdbl[1] + sdbl[2]) * (1.0 / 192.0));
}

extern "C" void kernel_launch(void* const* d_in, const int* in_sizes, int n_in,
                              void* d_out, int out_size, void* d_ws, size_t ws_size,
                              hipStream_t stream)
{
    const float* vx   = (const float*)d_in[0];
    const float* vy   = (const float*)d_in[1];
    const float* vz   = (const float*)d_in[2];
    const float* p    = (const float*)d_in[3];
    const float* mask = (const float*)d_in[4];
    const float* rvx  = (const float*)d_in[5];
    const float* rvy  = (const float*)d_in[6];
    const float* rvz  = (const float*)d_in[7];
    const float* rp   = (const float*)d_in[8];

    int R = (int)(ws_size / (ACC_FLOATS * sizeof(float)));
    if (R < 1)  R = 1;
    if (R > 64) R = 64;

    float* acc = (float*)d_ws;
    hipMemsetAsync(acc, 0, (size_t)R * ACC_FLOATS * sizeof(float), stream);

    slice_main<<<NBLK, 256, 0, stream>>>(vx, vy, vz, p, mask,
                                         rvx, rvy, rvz, rp, acc, R);
    slice_final<<<1, 1024, 0, stream>>>(acc, (float*)d_out, R);
}

// Round 6
// 50.258 us; speedup vs baseline: 1.6239x; 1.6239x over previous
//
#include <hip/hip_runtime.h>

#define GRID_N 192
constexpr int NROWS = GRID_N * GRID_N;    // 36864 rows of 192 floats (h contiguous)
constexpr int RPB   = 48;                 // rows per block; block = one l, 48 consecutive w
constexpr int NBLK  = NROWS / RPB;        // 768 blocks = exactly 3/CU resident -> zero tail
constexpr int RPW   = RPB / 4;            // 12 rows per wave (6 pairs)
constexpr int R_REP = 16;                 // accumulator replicas

// Replicated accumulator: R copies of 1152 floats, replica = blockIdx % R.
//   [0..191]    hD   [192..383]  hM
//   [384..575]  lD   [576..767]  lM
//   [768..959]  wD   [960..1151] wM
constexpr int ACC_FLOATS = 1152;

#define LOAD_ROW(P, base) \
    P##0 = *(const float4*)(rvx + (base)); P##1 = *(const float4*)(vx + (base)); \
    P##2 = *(const float4*)(rvy + (base)); P##3 = *(const float4*)(vy + (base)); \
    P##4 = *(const float4*)(rvz + (base)); P##5 = *(const float4*)(vz + (base)); \
    P##6 = *(const float4*)(rp  + (base)); P##7 = *(const float4*)(p  + (base)); \
    P##8 = *(const float4*)(mask + (base));

__global__ __launch_bounds__(256) void slice_main(
    const float* __restrict__ vx,  const float* __restrict__ vy,
    const float* __restrict__ vz,  const float* __restrict__ p,
    const float* __restrict__ mask,
    const float* __restrict__ rvx, const float* __restrict__ rvy,
    const float* __restrict__ rvz, const float* __restrict__ rp,
    float* __restrict__ acc)
{
    const int tid  = threadIdx.x;
    const int wv   = tid >> 6;
    const int lane = tid & 63;
    const bool act = lane < 48;           // 48 lanes x float4 = one 192-float row
    const int hb   = lane << 2;

    float* __restrict__ racc = acc + (size_t)(blockIdx.x % R_REP) * ACC_FLOATS;

    const int l  = blockIdx.x >> 2;               // 4 blocks per l-plane
    const int w0 = (blockIdx.x & 3) * RPB;        // 48 consecutive w per block
    const int rowbase = l * GRID_N + w0 + wv * RPW;

    __shared__ float sD[4][192];
    __shared__ float sM[4][192];
    __shared__ float sRowD[RPB][49];              // [local w][lane], padded
    __shared__ float sRowM[RPB][49];
    __shared__ float sL[2][4];

    float cD0=0.f,cD1=0.f,cD2=0.f,cD3=0.f;
    float cM0=0.f,cM1=0.f,cM2=0.f,cM3=0.f;

    // process rows in pairs: force all 18 float4 loads in flight before use
#pragma unroll 1
    for (int i = 0; i < RPW / 2; ++i) {
        const int rowA = rowbase + 2 * i;
        float4 A0,A1,A2,A3,A4,A5,A6,A7,A8;
        float4 B0,B1,B2,B3,B4,B5,B6,B7,B8;
        if (act) {
            const size_t baseA = (size_t)rowA * GRID_N + hb;
            const size_t baseB = baseA + GRID_N;
            LOAD_ROW(A, baseA)
            LOAD_ROW(B, baseB)
            __builtin_amdgcn_sched_barrier(0);   // keep the 18-load window intact

            float dA0 = (A0.x-A1.x) + (A2.x-A3.x) + (A4.x-A5.x) + (A6.x-A7.x);
            float dA1 = (A0.y-A1.y) + (A2.y-A3.y) + (A4.y-A5.y) + (A6.y-A7.y);
            float dA2 = (A0.z-A1.z) + (A2.z-A3.z) + (A4.z-A5.z) + (A6.z-A7.z);
            float dA3 = (A0.w-A1.w) + (A2.w-A3.w) + (A4.w-A5.w) + (A6.w-A7.w);
            float dB0 = (B0.x-B1.x) + (B2.x-B3.x) + (B4.x-B5.x) + (B6.x-B7.x);
            float dB1 = (B0.y-B1.y) + (B2.y-B3.y) + (B4.y-B5.y) + (B6.y-B7.y);
            float dB2 = (B0.z-B1.z) + (B2.z-B3.z) + (B4.z-B5.z) + (B6.z-B7.z);
            float dB3 = (B0.w-B1.w) + (B2.w-B3.w) + (B4.w-B5.w) + (B6.w-B7.w);

            cD0 += dA0 + dB0; cD1 += dA1 + dB1;
            cD2 += dA2 + dB2; cD3 += dA3 + dB3;
            cM0 += A8.x + B8.x; cM1 += A8.y + B8.y;
            cM2 += A8.z + B8.z; cM3 += A8.w + B8.w;

            const int lr = wv * RPW + 2 * i;
            sRowD[lr][lane]     = (dA0 + dA1) + (dA2 + dA3);
            sRowM[lr][lane]     = (A8.x + A8.y) + (A8.z + A8.w);
            sRowD[lr + 1][lane] = (dB0 + dB1) + (dB2 + dB3);
            sRowM[lr + 1][lane] = (B8.x + B8.y) + (B8.z + B8.w);
        }
    }

    if (act) {
        sD[wv][hb+0]=cD0; sD[wv][hb+1]=cD1; sD[wv][hb+2]=cD2; sD[wv][hb+3]=cD3;
        sM[wv][hb+0]=cM0; sM[wv][hb+1]=cM1; sM[wv][hb+2]=cM2; sM[wv][hb+3]=cM3;
    }
    __syncthreads();

    // h columns: one atomic per h per block into this block's replica
    float d = 0.f, m = 0.f;
    if (tid < 192) {
        d = (sD[0][tid] + sD[1][tid]) + (sD[2][tid] + sD[3][tid]);
        m = (sM[0][tid] + sM[1][tid]) + (sM[2][tid] + sM[3][tid]);
        atomicAdd(&racc[tid],       d);
        atomicAdd(&racc[192 + tid], m);
    }
    // w slots: reduce sRow[w][0..47], one atomic pair per local w
    if (tid < RPB) {
        float wd = 0.f, wm = 0.f;
#pragma unroll 8
        for (int i = 0; i < 48; ++i) { wd += sRowD[tid][i]; wm += sRowM[tid][i]; }
        atomicAdd(&racc[768 + w0 + tid], wd);
        atomicAdd(&racc[960 + w0 + tid], wm);
    }
    // l plane-partial = sum of this block's h-column totals
    {
        float td = d, tm = m;
#pragma unroll
        for (int off = 32; off; off >>= 1) {
            td += __shfl_xor(td, off);
            tm += __shfl_xor(tm, off);
        }
        if (lane == 0) { sL[0][wv] = td; sL[1][wv] = tm; }
    }
    __syncthreads();
    if (tid == 0) {
        atomicAdd(&racc[384 + l], (sL[0][0]+sL[0][1])+(sL[0][2]+sL[0][3]));
        atomicAdd(&racc[576 + l], (sL[1][0]+sL[1][1])+(sL[1][2]+sL[1][3]));
    }
}

__global__ __launch_bounds__(1024) void slice_final(const float* __restrict__ acc,
                                                    float* __restrict__ out)
{
    const int tid = threadIdx.x;
    __shared__ float ssum[ACC_FLOATS];
    __shared__ double sdbl[3];

    // phase 1: float4 replica reduction, 288 quads, independent loads per r
    if (tid < ACC_FLOATS / 4) {
        float4 v = make_float4(0.f, 0.f, 0.f, 0.f);
        const float4* a4 = (const float4*)acc;
#pragma unroll
        for (int r = 0; r < R_REP; ++r) {
            float4 x = a4[r * (ACC_FLOATS / 4) + tid];
            v.x += x.x; v.y += x.y; v.z += x.z; v.w += x.w;
        }
        ((float4*)ssum)[tid] = v;
    }
    __syncthreads();

    // phase 2: per-slice terms in fp64, then mean
    if (tid < 192) {
        double term = (double)ssum[384 + tid] / (double)ssum[576 + tid]
                    + (double)ssum[768 + tid] / (double)ssum[960 + tid]
                    + (double)ssum[tid]       / (double)ssum[192 + tid];
#pragma unroll
        for (int off = 32; off; off >>= 1) term += __shfl_xor(term, off);
        if ((tid & 63) == 0) sdbl[tid >> 6] = term;
    }
    __syncthreads();
    if (tid == 0) out[0] = (float)((sdbl[0] + sdbl[1] + sdbl[2]) * (1.0 / 192.0));
}

extern "C" void kernel_launch(void* const* d_in, const int* in_sizes, int n_in,
                              void* d_out, int out_size, void* d_ws, size_t ws_size,
                              hipStream_t stream)
{
    const float* vx   = (const float*)d_in[0];
    const float* vy   = (const float*)d_in[1];
    const float* vz   = (const float*)d_in[2];
    const float* p    = (const float*)d_in[3];
    const float* mask = (const float*)d_in[4];
    const float* rvx  = (const float*)d_in[5];
    const float* rvy  = (const float*)d_in[6];
    const float* rvz  = (const float*)d_in[7];
    const float* rp   = (const float*)d_in[8];

    float* acc = (float*)d_ws;
    hipMemsetAsync(acc, 0, (size_t)R_REP * ACC_FLOATS * sizeof(float), stream);

    slice_main<<<NBLK, 256, 0, stream>>>(vx, vy, vz, p, mask,
                                         rvx, rvy, rvz, rp, acc);
    slice_final<<<1, 1024, 0, stream>>>(acc, (float*)d_out);
}